// Round 11
// baseline (610.493 us; speedup 1.0000x reference)
//
#include <hip/hip_runtime.h>
#include <hip/hip_bf16.h>

// CapsuleLayer routing: ONE persistent kernel, manual grid barriers.
// B=512,P=1152,N=10,T=16,D=8, 3 iters. Verified 16x16x32 bf16 layouts:
//   A: m=lane&15, k=q*8+j   B: n=lane&15, k=q*8+j   D: col=lane&15, row=q*4+r
// Phases (5 grid barriers): prep (Xb/Xga/Wc0/Wb from one x read via LDS
// transpose tile) -> S0 -> G0 -> S1 -> G1 -> S2(writes d_out).
// Grid 256 blocks x 256 thr: <=4 waves, ~31KB LDS, ~120 VGPR => >=4 blocks/CU
// capacity, so all 256 blocks co-resident -> spin barrier is safe.
// ws is poisoned 0xAA each replay: block0 zeroes counters then release-stores
// MAGIC (!= 0xAAAAAAAA); all blocks acquire-spin on MAGIC before barrier use.

typedef __attribute__((ext_vector_type(8))) short bfrag;   // 8 bf16
typedef __attribute__((ext_vector_type(4))) float f32x4;

constexpr int B_ = 512, P_ = 1152, N_ = 10, NT_ = 160;
constexpr int K1_ = 9216, NKC_ = 288;
constexpr int GRID_ = 256;
#define MAGIC_ 0x13579BDF

__device__ __forceinline__ unsigned short f2bf(float f) {
    unsigned u = __float_as_uint(f);
    return (unsigned short)((u + 0x7fffu + ((u >> 16) & 1u)) >> 16);  // RNE
}
__device__ __forceinline__ float bf2f(unsigned short s) {
    return __uint_as_float((unsigned)s << 16);
}
__device__ __forceinline__ bfrag mkfrag(f32x4 a, f32x4 b, float c) {
    bfrag f;
    f[0] = (short)f2bf(a.x * c); f[1] = (short)f2bf(a.y * c);
    f[2] = (short)f2bf(a.z * c); f[3] = (short)f2bf(a.w * c);
    f[4] = (short)f2bf(b.x * c); f[5] = (short)f2bf(b.y * c);
    f[6] = (short)f2bf(b.z * c); f[7] = (short)f2bf(b.w * c);
    return f;
}

__device__ __forceinline__ void gridbar(int* sync, int k) {
    __syncthreads();
    __threadfence();                       // publish this block's writes (agent)
    if (threadIdx.x == 0) {
        __hip_atomic_fetch_add(&sync[k], 1, __ATOMIC_RELEASE, __HIP_MEMORY_SCOPE_AGENT);
        while (__hip_atomic_load(&sync[k], __ATOMIC_ACQUIRE, __HIP_MEMORY_SCOPE_AGENT) < GRID_)
            __builtin_amdgcn_s_sleep(8);
    }
    __syncthreads();
    __threadfence();                       // acquire side
}

// Xb:  [mblk 32][kc 288][lane 64][8]  elem = x[mblk*16+col][kc*32+q*8+j]
// Xga: [pdblk 576][kc 16][lane 64][8] elem = x[kc*32+q*8+j][pdblk*16+col]
// Wc:  [n 10][kc 288][lane 64][8]     elem = c[p,n]*W[p][n*16+col][j], p=kc*4+q
// Wb:  [pdblk 576][lane 64][40]       elem(mt*4+r) = W[p][mt*16+q*4+r][d]
__global__ __launch_bounds__(256) void k_all(const float* __restrict__ x,
                                             const float* __restrict__ W,
                                             float* __restrict__ bbar,
                                             unsigned short* __restrict__ Xb,
                                             unsigned short* __restrict__ Xga,
                                             unsigned short* __restrict__ Wc,
                                             unsigned short* __restrict__ Wb,
                                             unsigned short* __restrict__ Vt,
                                             float* __restrict__ outp,
                                             int* sync) {
    __shared__ union {
        unsigned short tile[64][72];                              // prep
        float red[3 * 256];                                       // S reduce
        struct { float bred[3][64][40]; float csm[2][N_]; } g;    // G
    } sm;
    const int tid = threadIdx.x, bid = blockIdx.x;
    const int w = tid >> 6, lane = tid & 63, col = lane & 15, q = lane >> 4;

    // ---- init handshake (ws poisoned 0xAA each call)
    if (bid == 0 && tid == 0) {
        for (int i = 1; i <= 5; ++i)
            __hip_atomic_store(&sync[i], 0, __ATOMIC_RELAXED, __HIP_MEMORY_SCOPE_AGENT);
        __hip_atomic_store(&sync[0], MAGIC_, __ATOMIC_RELEASE, __HIP_MEMORY_SCOPE_AGENT);
    }
    if (tid == 0)
        while (__hip_atomic_load(&sync[0], __ATOMIC_ACQUIRE, __HIP_MEMORY_SCOPE_AGENT) != MAGIC_)
            __builtin_amdgcn_s_sleep(8);
    __syncthreads();

    // ---- prep: 1152 x-tiles (Xga+Xb) + 720 Wc0 + 144 Wb sub-blocks
    for (int sb = bid; sb < 2016; sb += GRID_) {
        if (sb < 1152) {
            const int pd0 = (sb >> 3) * 64, b0 = (sb & 7) * 64;
            const int c0 = tid & 63, r0 = tid >> 6;
            __syncthreads();               // protect tile from previous round
#pragma unroll
            for (int i = 0; i < 16; ++i) {
                const int br = i * 4 + r0;
                sm.tile[c0][br] = f2bf(x[(size_t)(b0 + br) * K1_ + pd0 + c0]);
            }
            __syncthreads();
            for (int t2 = tid; t2 < 512; t2 += 256) {      // Xga frags
                const int pd_l = t2 >> 3, oct = t2 & 7;
                const int pd = pd0 + pd_l, b = b0 + oct * 8;
                bfrag f;
#pragma unroll
                for (int j = 0; j < 8; ++j) f[j] = (short)sm.tile[pd_l][oct * 8 + j];
                const size_t addr = ((size_t)((pd >> 4) * 16 + (b >> 5))) * 512
                                  + ((b >> 3) & 3) * 128 + (pd & 15) * 8;
                *(bfrag*)(Xga + addr) = f;
            }
            for (int t3 = tid; t3 < 512; t3 += 256) {      // Xb frags (8 tiles)
                const int tl = t3 >> 6, ln = t3 & 63;
                const int cl2 = ln & 15, q2 = ln >> 4;
                const int mb_l = tl >> 1, kc_l = tl & 1;
                const int mblk = (b0 >> 4) + mb_l, kc = (pd0 >> 5) + kc_l;
                bfrag f;
#pragma unroll
                for (int j = 0; j < 8; ++j)
                    f[j] = (short)sm.tile[kc_l * 32 + q2 * 8 + j][mb_l * 16 + cl2];
                *(bfrag*)(Xb + ((size_t)(mblk * NKC_ + kc)) * 512 + ln * 8) = f;
            }
        } else if (sb < 1872) {            // Wc0 = bf16(0.1*W), B-frag layout
            const int idx = (sb - 1152) * 256 + tid;
            const int p = idx / NT_, nt = idx % NT_, n = nt >> 4, cl = nt & 15;
            const float* wr = W + (size_t)idx * 8;
            const size_t addr = ((size_t)(n * NKC_ + (p >> 2))) * 512 + (p & 3) * 128 + cl * 8;
            *(bfrag*)(Wc + addr) = mkfrag(*(const f32x4*)wr, *(const f32x4*)(wr + 4), 0.1f);
        } else {                           // Wb contraction-layout bf16 W
            const int idx = (sb - 1872) * 256 + tid;
            const int ln = idx & 63;
            const int cl = ln & 15, q2 = ln >> 4;
            const int p = ((idx >> 6) * 16 + cl) >> 3, d = cl & 7;
            unsigned short* dst = Wb + (size_t)idx * 40;
#pragma unroll
            for (int mt = 0; mt < N_; ++mt)
#pragma unroll
                for (int r = 0; r < 4; ++r)
                    dst[mt * 4 + r] = f2bf(W[((size_t)p * NT_ + mt * 16 + q2 * 4 + r) * 8 + d]);
        }
    }
    gridbar(sync, 1);

    for (int it = 0; it < 3; ++it) {
        // ---- S: GEMM1 + squash. 320 tasks (mblk,n0), 4-wave split-K(288)
        for (int task = bid; task < 320; task += GRID_) {
            const int mblk = task & 31, n0 = task >> 5;
            f32x4 acc = (f32x4){0.f, 0.f, 0.f, 0.f};
            const unsigned short* Xp = Xb + ((size_t)(mblk * NKC_ + w * 72)) * 512 + lane * 8;
            const unsigned short* W0 = Wc + ((size_t)(n0 * NKC_ + w * 72)) * 512 + lane * 8;
#pragma unroll 6
            for (int i = 0; i < 72; ++i) {
                const bfrag a = *(const bfrag*)Xp;
                const bfrag b = *(const bfrag*)W0;
                acc = __builtin_amdgcn_mfma_f32_16x16x32_bf16(a, b, acc, 0, 0, 0);
                Xp += 512; W0 += 512;
            }
            if (w) {
#pragma unroll
                for (int r = 0; r < 4; ++r)
                    sm.red[(w - 1) * 256 + r * 64 + q * 16 + col] = acc[r];
            }
            __syncthreads();
            if (w == 0) {
#pragma unroll
                for (int r = 0; r < 4; ++r) {
                    const int li = r * 64 + q * 16 + col;
                    float s = acc[r] + sm.red[li] + sm.red[256 + li] + sm.red[512 + li];
                    float sq = s * s;                     // t = col (16 lanes)
                    sq += __shfl_xor(sq, 1);
                    sq += __shfl_xor(sq, 2);
                    sq += __shfl_xor(sq, 4);
                    sq += __shfl_xor(sq, 8);
                    const float norm = sqrtf(sq);
                    const float scale = sq / (1.0f + sq * (norm + 1e-9f));
                    const float vv = s * scale;
                    const int b = mblk * 16 + q * 4 + r;
                    const int nt = n0 * 16 + col;
                    if (it == 2) outp[(size_t)b * NT_ + nt] = vv;
                    else         Vt[(size_t)nt * B_ + b] = f2bf(vv);
                }
            }
            __syncthreads();
        }
        if (it == 2) return;
        gridbar(sync, 2 * it + 2);        // Vt ready

        // ---- G: GEMM2 + contraction + softmax + Wc rebuild. 576 tasks
        for (int pdblk = bid; pdblk < 576; pdblk += GRID_) {
            const int p = (pdblk * 16 + col) >> 3, d = col & 7;
            f32x4 acc[N_];
#pragma unroll
            for (int mt = 0; mt < N_; ++mt) acc[mt] = (f32x4){0.f, 0.f, 0.f, 0.f};
            const int kb0 = w * 4;
#pragma unroll
            for (int kc = kb0; kc < kb0 + 4; ++kc) {
                const bfrag bf = *(const bfrag*)(Xga + ((size_t)(pdblk * 16 + kc)) * 512 + lane * 8);
#pragma unroll
                for (int mt = 0; mt < N_; ++mt) {
                    const bfrag af = *(const bfrag*)(Vt + (size_t)(mt * 16 + col) * B_ + kc * 32 + q * 8);
                    acc[mt] = __builtin_amdgcn_mfma_f32_16x16x32_bf16(af, bf, acc[mt], 0, 0, 0);
                }
            }
            if (w) {
#pragma unroll
                for (int mt = 0; mt < N_; ++mt)
#pragma unroll
                    for (int r = 0; r < 4; ++r)
                        sm.g.bred[w - 1][lane][mt * 4 + r] = acc[mt][r];
            }
            __syncthreads();
            if (w == 0) {
                unsigned short wv[40];
                const unsigned short* ws2 = Wb + ((size_t)(pdblk * 64 + lane)) * 40;
#pragma unroll
                for (int v = 0; v < 40; ++v) wv[v] = ws2[v];
                float part[N_];
#pragma unroll
                for (int mt = 0; mt < N_; ++mt) {
                    float s = 0.f;
#pragma unroll
                    for (int r = 0; r < 4; ++r) {
                        const float h = acc[mt][r] + sm.g.bred[0][lane][mt * 4 + r]
                                      + sm.g.bred[1][lane][mt * 4 + r]
                                      + sm.g.bred[2][lane][mt * 4 + r];
                        s = fmaf(bf2f(wv[mt * 4 + r]), h, s);
                    }
                    s += __shfl_xor(s, 1);    // reduce over d
                    s += __shfl_xor(s, 2);
                    s += __shfl_xor(s, 4);
                    s += __shfl_xor(s, 16);   // reduce over t-quarters
                    s += __shfl_xor(s, 32);
                    part[mt] = s;
                }
                if (q == 0 && d == 0) {       // lanes 0 & 8: the block's 2 p's
                    const int pl = col >> 3;
                    float bv[N_];
#pragma unroll
                    for (int mt = 0; mt < N_; ++mt) {
                        bv[mt] = part[mt] * (1.0f / 512.0f);
                        if (it) bv[mt] += bbar[(size_t)p * N_ + mt];
                        bbar[(size_t)p * N_ + mt] = bv[mt];
                    }
                    float m = -1e30f;
#pragma unroll
                    for (int mt = 0; mt < N_; ++mt) m = fmaxf(m, bv[mt]);
                    float sum = 0.f;
#pragma unroll
                    for (int mt = 0; mt < N_; ++mt) { bv[mt] = __expf(bv[mt] - m); sum += bv[mt]; }
                    const float inv = 1.f / sum;
#pragma unroll
                    for (int mt = 0; mt < N_; ++mt) sm.g.csm[pl][mt] = bv[mt] * inv;
                }
            }
            __syncthreads();
            const int p0 = pdblk * 2;
            for (int t4 = tid; t4 < 320; t4 += 256) {      // Wc rebuild (2 p's)
                const int pl = t4 / 160, rem = t4 % 160;
                const int n = rem >> 4, cl = rem & 15;
                const int pp = p0 + pl;
                const float c = sm.g.csm[pl][n];
                const float* wr = W + ((size_t)pp * NT_ + n * 16 + cl) * 8;
                const size_t addr = ((size_t)(n * NKC_ + (pp >> 2))) * 512 + (pp & 3) * 128 + cl * 8;
                *(bfrag*)(Wc + addr) = mkfrag(*(const f32x4*)wr, *(const f32x4*)(wr + 4), c);
            }
            __syncthreads();
        }
        gridbar(sync, 2 * it + 3);        // Wc/bbar ready
    }
}

extern "C" void kernel_launch(void* const* d_in, const int* in_sizes, int n_in,
                              void* d_out, int out_size, void* d_ws, size_t ws_size,
                              hipStream_t stream) {
    const float* x = (const float*)d_in[0];   // fp32 [B][P*D]
    const float* W = (const float*)d_in[1];   // fp32 [P][NT][D]

    char* wsp = (char*)d_ws;
    int* sync = (int*)wsp;                                          // 256 B
    float* bbar = (float*)(wsp + 256);                              // 46080 B
    unsigned short* Xb  = (unsigned short*)(wsp + 46336);           // 9.44 MB
    unsigned short* Xga = Xb + (size_t)32 * NKC_ * 512;             // 9.44 MB
    unsigned short* Wc  = Xga + (size_t)576 * 16 * 512;             // 2.95 MB
    unsigned short* Wb  = Wc + (size_t)N_ * NKC_ * 512;             // 2.95 MB
    unsigned short* Vt  = Wb + (size_t)576 * 64 * 40;               // 160 KB
    float* outp = (float*)d_out;

    k_all<<<dim3(GRID_), dim3(256), 0, stream>>>(x, W, bbar, Xb, Xga, Wc, Wb,
                                                 Vt, outp, sync);
}

// Round 12
// 154.898 us; speedup vs baseline: 3.9412x; 3.9412x over previous
//
#include <hip/hip_runtime.h>
#include <hip/hip_bf16.h>

// CapsuleLayer routing, bf16 MFMA, 6 dispatches (r10 structure, prep rebuilt).
// B=512,P=1152,N=10,T=16,D=8, 3 iters. Verified 16x16x32 bf16 layouts:
//   A: m=lane&15, k=q*8+j   B: n=lane&15, k=q*8+j   D: col=lane&15, row=q*4+r
// Lesson r11: grid-wide barriers require agent-scope fences which nuke the
// non-coherent per-XCD L2s -> everything re-streams from HBM (610us). The
// 6-dispatch chain is the structural minimum.
// k_prep (rebuilt): 64x64 LDS transpose tile reads x ONCE (coalesced 256B
//   rows) and emits BOTH Xga and Xb fragments as 1KB/wave coalesced stores;
//   plus Wc0=bf16(0.1*W) and Wb ranges. 2016 virtual blocks.
// k_sv / k_ga: bit-identical to round 10 (passing, fastest).

typedef __attribute__((ext_vector_type(8))) short bfrag;   // 8 bf16
typedef __attribute__((ext_vector_type(4))) float f32x4;

constexpr int B_ = 512, P_ = 1152, N_ = 10, NT_ = 160;
constexpr int K1_ = 9216, NKC_ = 288;

__device__ __forceinline__ unsigned short f2bf(float f) {
    unsigned u = __float_as_uint(f);
    return (unsigned short)((u + 0x7fffu + ((u >> 16) & 1u)) >> 16);  // RNE
}
__device__ __forceinline__ float bf2f(unsigned short s) {
    return __uint_as_float((unsigned)s << 16);
}
__device__ __forceinline__ bfrag mkfrag(f32x4 a, f32x4 b, float c) {
    bfrag f;
    f[0] = (short)f2bf(a.x * c); f[1] = (short)f2bf(a.y * c);
    f[2] = (short)f2bf(a.z * c); f[3] = (short)f2bf(a.w * c);
    f[4] = (short)f2bf(b.x * c); f[5] = (short)f2bf(b.y * c);
    f[6] = (short)f2bf(b.z * c); f[7] = (short)f2bf(b.w * c);
    return f;
}

// Xb:  [mblk 32][kc 288][lane 64][8]  elem = x[mblk*16+col][kc*32+q*8+j]
// Xga: [pdblk 576][kc 16][lane 64][8] elem = x[kc*32+q*8+j][pdblk*16+col]
// Wc:  [n 10][kc 288][lane 64][8]     elem = c[p,n]*W[p][n*16+col][j], p=kc*4+q
// Wb:  [pdblk 576][lane 64][40]       elem(mt*4+r) = W[p][mt*16+q*4+r][d]
__global__ __launch_bounds__(256) void k_prep(const float* __restrict__ x,
                                              const float* __restrict__ W,
                                              unsigned short* __restrict__ Xb,
                                              unsigned short* __restrict__ Xga,
                                              unsigned short* __restrict__ Wc,
                                              unsigned short* __restrict__ Wb) {
    const int bid = blockIdx.x, tid = threadIdx.x;
    if (bid < 1152) {          // x transpose tile -> Xga AND Xb fragments
        __shared__ unsigned short tile[64][72];   // [pd_local][b_local]
        const int pd0 = (bid >> 3) * 64, b0 = (bid & 7) * 64;
        const int c0 = tid & 63, r0 = tid >> 6;
        const int w = tid >> 6, ln = tid & 63, col = ln & 15, q = ln >> 4;
#pragma unroll
        for (int i = 0; i < 16; ++i) {
            const int br = i * 4 + r0;   // coalesced: 64 lanes x 4B contiguous
            tile[c0][br] = f2bf(x[(size_t)(b0 + br) * K1_ + pd0 + c0]);
        }
        __syncthreads();
        // Xga: 8 frags (pdblk_l 0..3, kc_l 0..1); wave w does f=w, f=w+4
#pragma unroll
        for (int fi = 0; fi < 2; ++fi) {
            const int f = w + fi * 4;
            const int pdblk_l = f & 3, kc_l = f >> 2;
            bfrag fr;
#pragma unroll
            for (int j = 0; j < 8; ++j)
                fr[j] = (short)tile[pdblk_l * 16 + col][kc_l * 32 + q * 8 + j];
            const size_t addr = ((size_t)(((pd0 >> 4) + pdblk_l) * 16 + (b0 >> 5) + kc_l)) * 512 + ln * 8;
            *(bfrag*)(Xga + addr) = fr;   // 1KB/wave contiguous
        }
        // Xb: 8 frags (mblk_l 0..3, kc_l 0..1); wave w does f=w, f=w+4
#pragma unroll
        for (int fi = 0; fi < 2; ++fi) {
            const int f = w + fi * 4;
            const int mblk_l = f & 3, kc_l = f >> 2;
            bfrag fr;
#pragma unroll
            for (int j = 0; j < 8; ++j)
                fr[j] = (short)tile[kc_l * 32 + q * 8 + j][mblk_l * 16 + col];
            const size_t addr = ((size_t)(((b0 >> 4) + mblk_l) * NKC_ + (pd0 >> 5) + kc_l)) * 512 + ln * 8;
            *(bfrag*)(Xb + addr) = fr;    // 1KB/wave contiguous
        }
    } else if (bid < 1872) {   // Wc0 = bf16(0.1*W), B-frag layout
        const int idx = (bid - 1152) * 256 + tid;   // < 184320
        const int p = idx / NT_, nt = idx % NT_, n = nt >> 4, cl = nt & 15;
        const float* wr = W + (size_t)idx * 8;
        const size_t addr = ((size_t)(n * NKC_ + (p >> 2))) * 512 + (p & 3) * 128 + cl * 8;
        *(bfrag*)(Wc + addr) = mkfrag(*(const f32x4*)wr, *(const f32x4*)(wr + 4), 0.1f);
    } else {                   // Wb: contraction-layout bf16 W
        const int idx = (bid - 1872) * 256 + tid;   // < 36864
        const int ln = idx & 63;
        const int cl = ln & 15, q2 = ln >> 4;
        const int p = ((idx >> 6) * 16 + cl) >> 3, d = cl & 7;
        unsigned short* dst = Wb + (size_t)idx * 40;
#pragma unroll
        for (int mt = 0; mt < N_; ++mt)
#pragma unroll
            for (int r = 0; r < 4; ++r)
                dst[mt * 4 + r] = f2bf(W[((size_t)p * NT_ + mt * 16 + q2 * 4 + r) * 8 + d]);
    }
}

// ---- GEMM1 + squash. grid (32,10), 512 thr = 8 waves, 36 K-chunks/wave ----
__global__ __launch_bounds__(512) void k_sv(const unsigned short* __restrict__ Xb,
                                            const unsigned short* __restrict__ Wc,
                                            unsigned short* __restrict__ Vt,
                                            float* __restrict__ outp,
                                            int final_it) {
    __shared__ float red[7 * 256];
    const int tid = threadIdx.x;
    const int w = tid >> 6, lane = tid & 63, col = lane & 15, q = lane >> 4;
    const int mblk = blockIdx.x;        // 16 b-rows
    const int n0 = blockIdx.y;          // one n per block

    f32x4 acc = (f32x4){0.f, 0.f, 0.f, 0.f};
    const int kc0 = w * (NKC_ / 8);     // 36 chunks per wave
    const unsigned short* Xp = Xb + ((size_t)(mblk * NKC_ + kc0)) * 512 + lane * 8;
    const unsigned short* W0 = Wc + ((size_t)(n0 * NKC_ + kc0)) * 512 + lane * 8;
#pragma unroll 6
    for (int i = 0; i < NKC_ / 8; ++i) {
        const bfrag a = *(const bfrag*)Xp;
        const bfrag b = *(const bfrag*)W0;
        acc = __builtin_amdgcn_mfma_f32_16x16x32_bf16(a, b, acc, 0, 0, 0);
        Xp += 512; W0 += 512;
    }
    if (w) {
#pragma unroll
        for (int r = 0; r < 4; ++r)
            red[(w - 1) * 256 + r * 64 + q * 16 + col] = acc[r];
    }
    __syncthreads();
    if (w == 0) {
#pragma unroll
        for (int r = 0; r < 4; ++r) {
            const int li = r * 64 + q * 16 + col;
            float s = acc[r];
#pragma unroll
            for (int j = 0; j < 7; ++j) s += red[j * 256 + li];
            float sq = s * s;                      // t = col (16 lanes)
            sq += __shfl_xor(sq, 1);
            sq += __shfl_xor(sq, 2);
            sq += __shfl_xor(sq, 4);
            sq += __shfl_xor(sq, 8);
            const float norm = sqrtf(sq);
            const float scale = sq / (1.0f + sq * (norm + 1e-9f));
            const float vv = s * scale;
            const int b = mblk * 16 + q * 4 + r;
            const int nt = n0 * 16 + col;
            if (final_it) outp[(size_t)b * NT_ + nt] = vv;
            else          Vt[(size_t)nt * B_ + b] = f2bf(vv);
        }
    }
}

// ---- GEMM2 + contraction + softmax + Wc rebuild. grid 576, 256 thr --------
__global__ __launch_bounds__(256) void k_ga(const unsigned short* __restrict__ Vt,
                                            const unsigned short* __restrict__ Xga,
                                            const unsigned short* __restrict__ Wb,
                                            const float* __restrict__ W,
                                            float* __restrict__ bbar,
                                            unsigned short* __restrict__ Wc,
                                            int accum) {
    __shared__ float bred[3][64][40];
    __shared__ float csm[2][N_];
    const int tid = threadIdx.x;
    const int w = tid >> 6, lane = tid & 63, col = lane & 15, q = lane >> 4;
    const int pdblk = blockIdx.x;
    const int p = (pdblk * 16 + col) >> 3, d = col & 7;

    f32x4 acc[N_];
#pragma unroll
    for (int mt = 0; mt < N_; ++mt) acc[mt] = (f32x4){0.f, 0.f, 0.f, 0.f};

    const int kb0 = w * 4;
#pragma unroll
    for (int kc = kb0; kc < kb0 + 4; ++kc) {
        const bfrag bf = *(const bfrag*)(Xga + ((size_t)(pdblk * 16 + kc)) * 512 + lane * 8);
#pragma unroll
        for (int mt = 0; mt < N_; ++mt) {
            const bfrag af = *(const bfrag*)(Vt + (size_t)(mt * 16 + col) * B_ + kc * 32 + q * 8);
            acc[mt] = __builtin_amdgcn_mfma_f32_16x16x32_bf16(af, bf, acc[mt], 0, 0, 0);
        }
    }
    if (w) {
#pragma unroll
        for (int mt = 0; mt < N_; ++mt)
#pragma unroll
            for (int r = 0; r < 4; ++r)
                bred[w - 1][lane][mt * 4 + r] = acc[mt][r];
    }
    __syncthreads();
    if (w == 0) {
        unsigned short wv[40];
        const unsigned short* ws2 = Wb + ((size_t)(pdblk * 64 + lane)) * 40;
#pragma unroll
        for (int v = 0; v < 40; ++v) wv[v] = ws2[v];
        float part[N_];
#pragma unroll
        for (int mt = 0; mt < N_; ++mt) {
            float s = 0.f;
#pragma unroll
            for (int r = 0; r < 4; ++r) {
                const float h = acc[mt][r] + bred[0][lane][mt * 4 + r]
                              + bred[1][lane][mt * 4 + r] + bred[2][lane][mt * 4 + r];
                s = fmaf(bf2f(wv[mt * 4 + r]), h, s);
            }
            s += __shfl_xor(s, 1);    // reduce over d
            s += __shfl_xor(s, 2);
            s += __shfl_xor(s, 4);
            s += __shfl_xor(s, 16);   // reduce over t-quarters
            s += __shfl_xor(s, 32);
            part[mt] = s;
        }
        if (q == 0 && d == 0) {       // lanes 0 and 8: the block's 2 p's
            const int pl = col >> 3;
            float bv[N_];
#pragma unroll
            for (int mt = 0; mt < N_; ++mt) {
                bv[mt] = part[mt] * (1.0f / 512.0f);
                if (accum) bv[mt] += bbar[(size_t)p * N_ + mt];
                bbar[(size_t)p * N_ + mt] = bv[mt];
            }
            float m = -1e30f;
#pragma unroll
            for (int mt = 0; mt < N_; ++mt) m = fmaxf(m, bv[mt]);
            float sum = 0.f;
#pragma unroll
            for (int mt = 0; mt < N_; ++mt) { bv[mt] = __expf(bv[mt] - m); sum += bv[mt]; }
            const float inv = 1.f / sum;
#pragma unroll
            for (int mt = 0; mt < N_; ++mt) csm[pl][mt] = bv[mt] * inv;
        }
    }
    __syncthreads();
    const int p0 = pdblk * 2;
#pragma unroll
    for (int task = tid; task < 320; task += 256) {   // Wc rebuild (2 p's)
        const int pl = task / 160, rem = task % 160;
        const int n = rem >> 4, cl = rem & 15;
        const int pp = p0 + pl;
        const float c = csm[pl][n];
        const float* wr = W + ((size_t)pp * NT_ + n * 16 + cl) * 8;
        const size_t addr = ((size_t)(n * NKC_ + (pp >> 2))) * 512 + (pp & 3) * 128 + cl * 8;
        *(bfrag*)(Wc + addr) = mkfrag(*(const f32x4*)wr, *(const f32x4*)(wr + 4), c);
    }
}

extern "C" void kernel_launch(void* const* d_in, const int* in_sizes, int n_in,
                              void* d_out, int out_size, void* d_ws, size_t ws_size,
                              hipStream_t stream) {
    const float* x = (const float*)d_in[0];   // fp32 [B][P*D]
    const float* W = (const float*)d_in[1];   // fp32 [P][NT][D]

    char* wsp = (char*)d_ws;
    float* bbar = (float*)wsp;                                      // 46080 B
    unsigned short* Xb  = (unsigned short*)(wsp + 46080);           // 9.44 MB
    unsigned short* Xga = Xb + (size_t)32 * NKC_ * 512;             // 9.44 MB
    unsigned short* Wc  = Xga + (size_t)576 * 16 * 512;             // 2.95 MB
    unsigned short* Wb  = Wc + (size_t)N_ * NKC_ * 512;             // 2.95 MB
    unsigned short* Vt  = Wb + (size_t)576 * 64 * 40;               // 160 KB
    float* outp = (float*)d_out;

    k_prep<<<dim3(2016), dim3(256), 0, stream>>>(x, W, Xb, Xga, Wc, Wb);
    k_sv<<<dim3(32, 10), dim3(512), 0, stream>>>(Xb, Wc, Vt, outp, 0);
    k_ga<<<dim3(576), dim3(256), 0, stream>>>(Vt, Xga, Wb, W, bbar, Wc, 0);
    k_sv<<<dim3(32, 10), dim3(512), 0, stream>>>(Xb, Wc, Vt, outp, 0);
    k_ga<<<dim3(576), dim3(256), 0, stream>>>(Vt, Xga, Wb, W, bbar, Wc, 1);
    k_sv<<<dim3(32, 10), dim3(512), 0, stream>>>(Xb, Wc, Vt, outp, 1);
}

// Round 13
// 154.681 us; speedup vs baseline: 3.9468x; 1.0014x over previous
//
#include <hip/hip_runtime.h>
#include <hip/hip_bf16.h>

// CapsuleLayer routing, bf16 MFMA, 6 dispatches (r12 structure + micro-opts).
// B=512,P=1152,N=10,T=16,D=8, 3 iters. Verified 16x16x32 bf16 layouts:
//   A: m=lane&15, k=q*8+j   B: n=lane&15, k=q*8+j   D: col=lane&15, row=q*4+r
// r13 changes vs r12 (both proven-passing structure):
//  - k_sv: dual accumulators (even/odd kc streams) halve the serial MFMA
//    dependency chain and double outstanding loads.
//  - k_prep Wc0 branch: one wave per (n,kc) -> 1KB/wave coalesced writes
//    (was 16B scattered by (p&3)*128). Same byte layout, same values.
// Chain prep -> sv0 -> ga0 -> sv1 -> ga1 -> sv2 is structurally minimal:
// r11 proved grid-wide sync costs 4x (agent fences nuke non-coherent XCD L2s).

typedef __attribute__((ext_vector_type(8))) short bfrag;   // 8 bf16
typedef __attribute__((ext_vector_type(4))) float f32x4;

constexpr int B_ = 512, P_ = 1152, N_ = 10, NT_ = 160;
constexpr int K1_ = 9216, NKC_ = 288;

__device__ __forceinline__ unsigned short f2bf(float f) {
    unsigned u = __float_as_uint(f);
    return (unsigned short)((u + 0x7fffu + ((u >> 16) & 1u)) >> 16);  // RNE
}
__device__ __forceinline__ float bf2f(unsigned short s) {
    return __uint_as_float((unsigned)s << 16);
}
__device__ __forceinline__ bfrag mkfrag(f32x4 a, f32x4 b, float c) {
    bfrag f;
    f[0] = (short)f2bf(a.x * c); f[1] = (short)f2bf(a.y * c);
    f[2] = (short)f2bf(a.z * c); f[3] = (short)f2bf(a.w * c);
    f[4] = (short)f2bf(b.x * c); f[5] = (short)f2bf(b.y * c);
    f[6] = (short)f2bf(b.z * c); f[7] = (short)f2bf(b.w * c);
    return f;
}

// Xb:  [mblk 32][kc 288][lane 64][8]  elem = x[mblk*16+col][kc*32+q*8+j]
// Xga: [pdblk 576][kc 16][lane 64][8] elem = x[kc*32+q*8+j][pdblk*16+col]
// Wc:  [n 10][kc 288][lane 64][8]     elem = c[p,n]*W[p][n*16+col][j], p=kc*4+q
// Wb:  [pdblk 576][lane 64][40]       elem(mt*4+r) = W[p][mt*16+q*4+r][d]
__global__ __launch_bounds__(256) void k_prep(const float* __restrict__ x,
                                              const float* __restrict__ W,
                                              unsigned short* __restrict__ Xb,
                                              unsigned short* __restrict__ Xga,
                                              unsigned short* __restrict__ Wc,
                                              unsigned short* __restrict__ Wb) {
    const int bid = blockIdx.x, tid = threadIdx.x;
    const int w = tid >> 6, ln = tid & 63, col = ln & 15, q = ln >> 4;
    if (bid < 1152) {          // x transpose tile -> Xga AND Xb fragments
        __shared__ unsigned short tile[64][72];   // [pd_local][b_local]
        const int pd0 = (bid >> 3) * 64, b0 = (bid & 7) * 64;
        const int c0 = tid & 63, r0 = tid >> 6;
#pragma unroll
        for (int i = 0; i < 16; ++i) {
            const int br = i * 4 + r0;   // coalesced: 64 lanes x 4B contiguous
            tile[c0][br] = f2bf(x[(size_t)(b0 + br) * K1_ + pd0 + c0]);
        }
        __syncthreads();
        // Xga: 8 frags (pdblk_l 0..3, kc_l 0..1); wave w does f=w, f=w+4
#pragma unroll
        for (int fi = 0; fi < 2; ++fi) {
            const int f = w + fi * 4;
            const int pdblk_l = f & 3, kc_l = f >> 2;
            bfrag fr;
#pragma unroll
            for (int j = 0; j < 8; ++j)
                fr[j] = (short)tile[pdblk_l * 16 + col][kc_l * 32 + q * 8 + j];
            const size_t addr = ((size_t)(((pd0 >> 4) + pdblk_l) * 16 + (b0 >> 5) + kc_l)) * 512 + ln * 8;
            *(bfrag*)(Xga + addr) = fr;   // 1KB/wave contiguous
        }
        // Xb: 8 frags (mblk_l 0..3, kc_l 0..1); wave w does f=w, f=w+4
#pragma unroll
        for (int fi = 0; fi < 2; ++fi) {
            const int f = w + fi * 4;
            const int mblk_l = f & 3, kc_l = f >> 2;
            bfrag fr;
#pragma unroll
            for (int j = 0; j < 8; ++j)
                fr[j] = (short)tile[kc_l * 32 + q * 8 + j][mblk_l * 16 + col];
            const size_t addr = ((size_t)(((b0 >> 4) + mblk_l) * NKC_ + (pd0 >> 5) + kc_l)) * 512 + ln * 8;
            *(bfrag*)(Xb + addr) = fr;    // 1KB/wave contiguous
        }
    } else if (bid < 1872) {   // Wc0 = bf16(0.1*W): one wave per (n,kc)
        const int task = (bid - 1152) * 4 + w;     // < 2880 = 10*288
        const int n = task / NKC_, kc = task % NKC_;
        const int p = kc * 4 + q;
        const float* wr = W + ((size_t)p * NT_ + n * 16 + col) * 8;
        const bfrag f = mkfrag(*(const f32x4*)wr, *(const f32x4*)(wr + 4), 0.1f);
        *(bfrag*)(Wc + ((size_t)(n * NKC_ + kc)) * 512 + ln * 8) = f;  // 1KB/wave
    } else {                   // Wb: contraction-layout bf16 W
        const int idx = (bid - 1872) * 256 + tid;   // < 36864
        const int p = ((idx >> 6) * 16 + (idx & 15)) >> 3, d = idx & 7;
        const int q2 = (idx & 63) >> 4;
        unsigned short* dst = Wb + (size_t)idx * 40;
#pragma unroll
        for (int mt = 0; mt < N_; ++mt)
#pragma unroll
            for (int r = 0; r < 4; ++r)
                dst[mt * 4 + r] = f2bf(W[((size_t)p * NT_ + mt * 16 + q2 * 4 + r) * 8 + d]);
    }
}

// ---- GEMM1 + squash. grid (32,10), 512 thr = 8 waves, 36 K-chunks/wave ----
// Dual accumulators: even/odd kc streams halve the MFMA dependency chain.
__global__ __launch_bounds__(512) void k_sv(const unsigned short* __restrict__ Xb,
                                            const unsigned short* __restrict__ Wc,
                                            unsigned short* __restrict__ Vt,
                                            float* __restrict__ outp,
                                            int final_it) {
    __shared__ float red[7 * 256];
    const int tid = threadIdx.x;
    const int w = tid >> 6, lane = tid & 63, col = lane & 15, q = lane >> 4;
    const int mblk = blockIdx.x;        // 16 b-rows
    const int n0 = blockIdx.y;          // one n per block

    f32x4 accA = (f32x4){0.f, 0.f, 0.f, 0.f};
    f32x4 accB = (f32x4){0.f, 0.f, 0.f, 0.f};
    const int kc0 = w * 36;             // 36 chunks per wave, processed 2/iter
    const unsigned short* Xp = Xb + ((size_t)(mblk * NKC_ + kc0)) * 512 + lane * 8;
    const unsigned short* W0 = Wc + ((size_t)(n0 * NKC_ + kc0)) * 512 + lane * 8;
#pragma unroll 3
    for (int i = 0; i < 18; ++i) {
        const bfrag a0 = *(const bfrag*)Xp;
        const bfrag b0 = *(const bfrag*)W0;
        const bfrag a1 = *(const bfrag*)(Xp + 512);
        const bfrag b1 = *(const bfrag*)(W0 + 512);
        accA = __builtin_amdgcn_mfma_f32_16x16x32_bf16(a0, b0, accA, 0, 0, 0);
        accB = __builtin_amdgcn_mfma_f32_16x16x32_bf16(a1, b1, accB, 0, 0, 0);
        Xp += 1024; W0 += 1024;
    }
    f32x4 acc;
#pragma unroll
    for (int r = 0; r < 4; ++r) acc[r] = accA[r] + accB[r];
    if (w) {
#pragma unroll
        for (int r = 0; r < 4; ++r)
            red[(w - 1) * 256 + r * 64 + q * 16 + col] = acc[r];
    }
    __syncthreads();
    if (w == 0) {
#pragma unroll
        for (int r = 0; r < 4; ++r) {
            const int li = r * 64 + q * 16 + col;
            float s = acc[r];
#pragma unroll
            for (int j = 0; j < 7; ++j) s += red[j * 256 + li];
            float sq = s * s;                      // t = col (16 lanes)
            sq += __shfl_xor(sq, 1);
            sq += __shfl_xor(sq, 2);
            sq += __shfl_xor(sq, 4);
            sq += __shfl_xor(sq, 8);
            const float norm = sqrtf(sq);
            const float scale = sq / (1.0f + sq * (norm + 1e-9f));
            const float vv = s * scale;
            const int b = mblk * 16 + q * 4 + r;
            const int nt = n0 * 16 + col;
            if (final_it) outp[(size_t)b * NT_ + nt] = vv;
            else          Vt[(size_t)nt * B_ + b] = f2bf(vv);
        }
    }
}

// ---- GEMM2 + contraction + softmax + Wc rebuild. grid 576, 256 thr --------
__global__ __launch_bounds__(256) void k_ga(const unsigned short* __restrict__ Vt,
                                            const unsigned short* __restrict__ Xga,
                                            const unsigned short* __restrict__ Wb,
                                            const float* __restrict__ W,
                                            float* __restrict__ bbar,
                                            unsigned short* __restrict__ Wc,
                                            int accum) {
    __shared__ float bred[3][64][40];
    __shared__ float csm[2][N_];
    const int tid = threadIdx.x;
    const int w = tid >> 6, lane = tid & 63, col = lane & 15, q = lane >> 4;
    const int pdblk = blockIdx.x;
    const int p = (pdblk * 16 + col) >> 3, d = col & 7;

    f32x4 acc[N_];
#pragma unroll
    for (int mt = 0; mt < N_; ++mt) acc[mt] = (f32x4){0.f, 0.f, 0.f, 0.f};

    const int kb0 = w * 4;
#pragma unroll
    for (int kc = kb0; kc < kb0 + 4; ++kc) {
        const bfrag bf = *(const bfrag*)(Xga + ((size_t)(pdblk * 16 + kc)) * 512 + lane * 8);
#pragma unroll
        for (int mt = 0; mt < N_; ++mt) {
            const bfrag af = *(const bfrag*)(Vt + (size_t)(mt * 16 + col) * B_ + kc * 32 + q * 8);
            acc[mt] = __builtin_amdgcn_mfma_f32_16x16x32_bf16(af, bf, acc[mt], 0, 0, 0);
        }
    }
    if (w) {
#pragma unroll
        for (int mt = 0; mt < N_; ++mt)
#pragma unroll
            for (int r = 0; r < 4; ++r)
                bred[w - 1][lane][mt * 4 + r] = acc[mt][r];
    }
    __syncthreads();
    if (w == 0) {
        unsigned short wv[40];
        const unsigned short* ws2 = Wb + ((size_t)(pdblk * 64 + lane)) * 40;
#pragma unroll
        for (int v = 0; v < 40; ++v) wv[v] = ws2[v];
        float part[N_];
#pragma unroll
        for (int mt = 0; mt < N_; ++mt) {
            float s = 0.f;
#pragma unroll
            for (int r = 0; r < 4; ++r) {
                const float h = acc[mt][r] + bred[0][lane][mt * 4 + r]
                              + bred[1][lane][mt * 4 + r] + bred[2][lane][mt * 4 + r];
                s = fmaf(bf2f(wv[mt * 4 + r]), h, s);
            }
            s += __shfl_xor(s, 1);    // reduce over d
            s += __shfl_xor(s, 2);
            s += __shfl_xor(s, 4);
            s += __shfl_xor(s, 16);   // reduce over t-quarters
            s += __shfl_xor(s, 32);
            part[mt] = s;
        }
        if (q == 0 && d == 0) {       // lanes 0 and 8: the block's 2 p's
            const int pl = col >> 3;
            float bv[N_];
#pragma unroll
            for (int mt = 0; mt < N_; ++mt) {
                bv[mt] = part[mt] * (1.0f / 512.0f);
                if (accum) bv[mt] += bbar[(size_t)p * N_ + mt];
                bbar[(size_t)p * N_ + mt] = bv[mt];
            }
            float m = -1e30f;
#pragma unroll
            for (int mt = 0; mt < N_; ++mt) m = fmaxf(m, bv[mt]);
            float sum = 0.f;
#pragma unroll
            for (int mt = 0; mt < N_; ++mt) { bv[mt] = __expf(bv[mt] - m); sum += bv[mt]; }
            const float inv = 1.f / sum;
#pragma unroll
            for (int mt = 0; mt < N_; ++mt) csm[pl][mt] = bv[mt] * inv;
        }
    }
    __syncthreads();
    const int p0 = pdblk * 2;
#pragma unroll
    for (int task = tid; task < 320; task += 256) {   // Wc rebuild (2 p's)
        const int pl = task / 160, rem = task % 160;
        const int n = rem >> 4, cl = rem & 15;
        const int pp = p0 + pl;
        const float c = csm[pl][n];
        const float* wr = W + ((size_t)pp * NT_ + n * 16 + cl) * 8;
        const size_t addr = ((size_t)(n * NKC_ + (pp >> 2))) * 512 + (pp & 3) * 128 + cl * 8;
        *(bfrag*)(Wc + addr) = mkfrag(*(const f32x4*)wr, *(const f32x4*)(wr + 4), c);
    }
}

extern "C" void kernel_launch(void* const* d_in, const int* in_sizes, int n_in,
                              void* d_out, int out_size, void* d_ws, size_t ws_size,
                              hipStream_t stream) {
    const float* x = (const float*)d_in[0];   // fp32 [B][P*D]
    const float* W = (const float*)d_in[1];   // fp32 [P][NT][D]

    char* wsp = (char*)d_ws;
    float* bbar = (float*)wsp;                                      // 46080 B
    unsigned short* Xb  = (unsigned short*)(wsp + 46080);           // 9.44 MB
    unsigned short* Xga = Xb + (size_t)32 * NKC_ * 512;             // 9.44 MB
    unsigned short* Wc  = Xga + (size_t)576 * 16 * 512;             // 2.95 MB
    unsigned short* Wb  = Wc + (size_t)N_ * NKC_ * 512;             // 2.95 MB
    unsigned short* Vt  = Wb + (size_t)576 * 64 * 40;               // 160 KB
    float* outp = (float*)d_out;

    k_prep<<<dim3(2016), dim3(256), 0, stream>>>(x, W, Xb, Xga, Wc, Wb);
    k_sv<<<dim3(32, 10), dim3(512), 0, stream>>>(Xb, Wc, Vt, outp, 0);
    k_ga<<<dim3(576), dim3(256), 0, stream>>>(Vt, Xga, Wb, W, bbar, Wc, 0);
    k_sv<<<dim3(32, 10), dim3(512), 0, stream>>>(Xb, Wc, Vt, outp, 0);
    k_ga<<<dim3(576), dim3(256), 0, stream>>>(Vt, Xga, Wb, W, bbar, Wc, 1);
    k_sv<<<dim3(32, 10), dim3(512), 0, stream>>>(Xb, Wc, Vt, outp, 1);
}